// Round 1
// baseline (1218.428 us; speedup 1.0000x reference)
//
#include <hip/hip_runtime.h>
#include <math.h>

#define S_LEN  2048
#define B_SZ   256
#define T_TAGS 48

// ---------------------------------------------------------------------------
// Forward algorithm (normalizer), linear-space with per-step renormalization.
// One wave (64 threads) per batch element. Lane j owns next-state j.
// score[j] = L + log(v[j]);  v'[j] = (sum_i v[i]*expT[i][j]) * exp(em[s,j]) / v[0]
// ---------------------------------------------------------------------------
__global__ __launch_bounds__(64, 1) void crf_forward_kernel(
    const float* __restrict__ em, const int* __restrict__ mask,
    const float* __restrict__ startT, const float* __restrict__ endT,
    const float* __restrict__ trans, float* __restrict__ out)
{
    const int b   = blockIdx.x;
    const int tid = threadIdx.x;                 // 0..63
    const int j   = (tid < T_TAGS) ? tid : 0;    // clamp lanes 48..63
    const bool active = (tid < T_TAGS);

    __shared__ __align__(16) float v_lds[T_TAGS];

    // expT column j in registers: expT[i] = exp(trans[i][j]) (constant over s,b)
    float expT[T_TAGS];
#pragma unroll
    for (int i = 0; i < T_TAGS; ++i)
        expT[i] = __expf(trans[i * T_TAGS + j]);

    const float endv = endT[j];

    // init: v[j] = exp(start[j] + em[0,b,j]), L = 0
    const float vinit = __expf(startT[j] + em[(size_t)b * T_TAGS + j]);
    if (active) v_lds[tid] = vinit;
    __builtin_amdgcn_wave_barrier();

    double L = 0.0;

    // emission/mask prefetch ring, depth 4 (covers ~900-cycle HBM latency)
    float em_pf[4];
    int   mk_pf[4];
#pragma unroll
    for (int k = 0; k < 4; ++k) {
        int ss = 1 + k; if (ss > S_LEN - 1) ss = S_LEN - 1;
        em_pf[k] = em[((size_t)ss * B_SZ + b) * T_TAGS + j];
        mk_pf[k] = mask[ss * B_SZ + b];
    }

#pragma unroll 4
    for (int s = 1; s < S_LEN; ++s) {
        const int   slot   = (s - 1) & 3;        // static under unroll-4
        const float em_cur = em_pf[slot];
        const int   mk_cur = mk_pf[slot];
        int sp = s + 4; if (sp > S_LEN - 1) sp = S_LEN - 1;
        em_pf[slot] = em[((size_t)sp * B_SZ + b) * T_TAGS + j];
        mk_pf[slot] = mask[sp * B_SZ + b];

        if (mk_cur != 0) {
            // broadcast-read all 48 v values (12 x ds_read_b128, no conflicts)
            float vv[T_TAGS];
#pragma unroll
            for (int q = 0; q < T_TAGS / 4; ++q) {
                const float4 t4 = *reinterpret_cast<const float4*>(&v_lds[4 * q]);
                vv[4 * q + 0] = t4.x; vv[4 * q + 1] = t4.y;
                vv[4 * q + 2] = t4.z; vv[4 * q + 3] = t4.w;
            }
            float a0 = 0.f, a1 = 0.f, a2 = 0.f, a3 = 0.f;
#pragma unroll
            for (int i = 0; i < T_TAGS; i += 4) {
                a0 = fmaf(vv[i + 0], expT[i + 0], a0);
                a1 = fmaf(vv[i + 1], expT[i + 1], a1);
                a2 = fmaf(vv[i + 2], expT[i + 2], a2);
                a3 = fmaf(vv[i + 3], expT[i + 3], a3);
            }
            const float ssum   = (a0 + a1) + (a2 + a3);
            const float vfirst = vv[0];
            const float r      = __builtin_amdgcn_rcpf(vfirst);
            const float vn     = ssum * r * __expf(em_cur);
            L += (double)__logf(vfirst);
            if (active) v_lds[tid] = vn;
        }
        __builtin_amdgcn_wave_barrier();
    }

    // denominator_b = L + log( sum_j v[j]*exp(end[j]) )
    float contrib = active ? v_lds[tid] * __expf(endv) : 0.0f;
#pragma unroll
    for (int off = 32; off > 0; off >>= 1)
        contrib += __shfl_down(contrib, off);
    if (tid == 0) {
        const float den = (float)(L + (double)__logf(contrib));
        atomicAdd(out, -den);
    }
}

// ---------------------------------------------------------------------------
// Numerator: emission scores of chosen tags + transition scores + start terms
// ---------------------------------------------------------------------------
__global__ void crf_num_kernel(
    const float* __restrict__ em, const int* __restrict__ tags,
    const int* __restrict__ mask, const float* __restrict__ startT,
    const float* __restrict__ trans, float* __restrict__ out)
{
    const int N = S_LEN * B_SZ;
    float acc = 0.f;
    for (int idx = blockIdx.x * blockDim.x + threadIdx.x; idx < N;
         idx += gridDim.x * blockDim.x) {
        const int t = tags[idx];
        const float e = em[(size_t)idx * T_TAGS + t];
        if (idx < B_SZ) {                         // s == 0
            acc += e + startT[t];
        } else if (mask[idx] != 0) {
            acc += e + trans[tags[idx - B_SZ] * T_TAGS + t];
        }
    }
#pragma unroll
    for (int off = 32; off > 0; off >>= 1)
        acc += __shfl_down(acc, off);
    if ((threadIdx.x & 63) == 0) atomicAdd(out, acc);
}

// ---------------------------------------------------------------------------
// End-transition terms: seq_ends = mask.sum(0) - 1; end[tags[seq_end, b]]
// ---------------------------------------------------------------------------
__global__ void crf_end_kernel(
    const int* __restrict__ tags, const int* __restrict__ mask,
    const float* __restrict__ endT, float* __restrict__ out)
{
    const int b = blockIdx.x * blockDim.x + threadIdx.x;
    float acc = 0.f;
    if (b < B_SZ) {
        int cnt = 0;
        for (int s = 0; s < S_LEN; ++s) cnt += (mask[s * B_SZ + b] != 0);
        const int last = tags[(size_t)(cnt - 1) * B_SZ + b];
        acc = endT[last];
    }
#pragma unroll
    for (int off = 32; off > 0; off >>= 1)
        acc += __shfl_down(acc, off);
    if ((threadIdx.x & 63) == 0) atomicAdd(out, acc);
}

extern "C" void kernel_launch(void* const* d_in, const int* in_sizes, int n_in,
                              void* d_out, int out_size, void* d_ws, size_t ws_size,
                              hipStream_t stream)
{
    const float* em     = (const float*)d_in[0];
    const int*   tags   = (const int*)  d_in[1];
    const int*   mask   = (const int*)  d_in[2];
    const float* startT = (const float*)d_in[3];
    const float* endT   = (const float*)d_in[4];
    const float* trans  = (const float*)d_in[5];
    float* out = (float*)d_out;

    hipMemsetAsync(out, 0, sizeof(float), stream);
    crf_forward_kernel<<<B_SZ, 64, 0, stream>>>(em, mask, startT, endT, trans, out);
    crf_num_kernel<<<512, 256, 0, stream>>>(em, tags, mask, startT, trans, out);
    crf_end_kernel<<<1, 256, 0, stream>>>(tags, mask, endT, out);
}